// Round 2
// baseline (321.825 us; speedup 1.0000x reference)
//
#include <hip/hip_runtime.h>

#define N_NODES  10000
#define N_EDGES  320000
#define N_GRAPHS 64
#define F 256

// ---------------- pipeline ----------------
// layer1 factors to scalars: h1[i,c] = relu(sfin[i]*W1[c]+b1[c]),
//   sfin[i] = dinv[i]*(sum_{e:dst=i} dinv[src]*x[src] + dinv[i]*x[i])
// layer2: aggregate dinv-scaled rows via CSR (one wave/node), scale by dinv,
//   then one [10000,256]x[256,256] GEMM (+bias, relu).
// pool: sorted-batch segment means. head: tiny per-graph MLP.

__global__ void k_prep(const int* batch, float* deg, float* s, int* gstart) {
    int i = blockIdx.x * blockDim.x + threadIdx.x;
    if (i >= N_NODES) return;
    deg[i] = 1.0f;              // self-loop
    s[i] = 0.0f;
    int b = batch[i];
    if (i == 0) {
        for (int g = 0; g <= b; g++) gstart[g] = 0;
    } else {
        int bp = batch[i - 1];
        for (int g = bp + 1; g <= b; g++) gstart[g] = i;
    }
    if (i == N_NODES - 1) {
        for (int g = b + 1; g <= N_GRAPHS; g++) gstart[g] = N_NODES;
    }
}

__global__ void k_deg(const int* dst, float* deg) {
    int e = blockIdx.x * blockDim.x + threadIdx.x;
    if (e < N_EDGES) atomicAdd(&deg[dst[e]], 1.0f);
}

__global__ void k_dinv(float* deg_dinv, int* cnti) {
    int i = blockIdx.x * blockDim.x + threadIdx.x;
    if (i >= N_NODES) return;
    float d = deg_dinv[i];
    cnti[i] = (int)d - 1;              // non-self-loop in-degree, exact in f32
    deg_dinv[i] = 1.0f / sqrtf(d);     // d >= 1 always
}

__global__ void k_s(const int* src, const int* dst, const float* x,
                    const float* dinv, float* s) {
    int e = blockIdx.x * blockDim.x + threadIdx.x;
    if (e >= N_EDGES) return;
    int sv = src[e];
    atomicAdd(&s[dst[e]], dinv[sv] * x[sv]);
}

// single-block exclusive scan of cnti -> offs, seeds cursor
__global__ void k_scan(const int* cnti, int* offs, int* cursor) {
    __shared__ int part[256];
    int t = threadIdx.x;
    const int CH = 40;                 // 256*40 >= 10000
    int lo = t * CH, hi = lo + CH;
    if (hi > N_NODES) hi = N_NODES;
    if (lo > N_NODES) lo = N_NODES;
    int sum = 0;
    for (int i = lo; i < hi; i++) sum += cnti[i];
    part[t] = sum;
    __syncthreads();
    for (int off = 1; off < 256; off <<= 1) {
        int v = (t >= off) ? part[t - off] : 0;
        __syncthreads();
        if (t >= off) part[t] += v;
        __syncthreads();
    }
    int base = (t == 0) ? 0 : part[t - 1];
    for (int i = lo; i < hi; i++) {
        offs[i] = base; cursor[i] = base; base += cnti[i];
    }
}

__global__ void k_fill(const int* src, const int* dst, int* cursor, int* csr) {
    int e = blockIdx.x * blockDim.x + threadIdx.x;
    if (e >= N_EDGES) return;
    int pos = atomicAdd(&cursor[dst[e]], 1);
    csr[pos] = src[e];
}

// out1s[i,c] = dinv[i] * relu(sfin[i]*W1[c] + b1[c])
__global__ void k_out1(const float* s, const float* dinv, const float* x,
                       const float* W1, const float* b1, float* out1s) {
    int idx = blockIdx.x * blockDim.x + threadIdx.x;
    if (idx >= N_NODES * F) return;
    int i = idx >> 8, c = idx & 255;
    float di = dinv[i];
    float sfin = di * (s[i] + di * x[i]);
    float v = sfin * W1[c] + b1[c];
    out1s[idx] = di * fmaxf(v, 0.0f);
}

// one wave per node: agg[i,:] = dinv[i]*(out1s[i,:] + sum_{sv in CSR[i]} out1s[sv,:])
// 4x unrolled edge walk for memory-level parallelism (L2/L3-resident gather).
__global__ __launch_bounds__(256) void k_agg(const float* out1s, const float* dinv,
                                             const int* offs, const int* cnti,
                                             const int* csr, float* agg) {
    int wid  = (blockIdx.x * blockDim.x + threadIdx.x) >> 6;
    int lane = threadIdx.x & 63;
    if (wid >= N_NODES) return;
    float4 acc = ((const float4*)(out1s + (size_t)wid * F))[lane];  // self-loop term
    int lo = offs[wid], n = cnti[wid];
    int j = 0;
    for (; j + 3 < n; j += 4) {
        int s0 = csr[lo + j], s1 = csr[lo + j + 1];
        int s2 = csr[lo + j + 2], s3 = csr[lo + j + 3];
        float4 v0 = ((const float4*)(out1s + (size_t)s0 * F))[lane];
        float4 v1 = ((const float4*)(out1s + (size_t)s1 * F))[lane];
        float4 v2 = ((const float4*)(out1s + (size_t)s2 * F))[lane];
        float4 v3 = ((const float4*)(out1s + (size_t)s3 * F))[lane];
        acc.x += v0.x + v1.x + v2.x + v3.x;
        acc.y += v0.y + v1.y + v2.y + v3.y;
        acc.z += v0.z + v1.z + v2.z + v3.z;
        acc.w += v0.w + v1.w + v2.w + v3.w;
    }
    for (; j < n; j++) {
        int sv = csr[lo + j];
        float4 v = ((const float4*)(out1s + (size_t)sv * F))[lane];
        acc.x += v.x; acc.y += v.y; acc.z += v.z; acc.w += v.w;
    }
    float di = dinv[wid];
    float4 o; o.x = acc.x * di; o.y = acc.y * di; o.z = acc.z * di; o.w = acc.w * di;
    ((float4*)(agg + (size_t)wid * F))[lane] = o;
}

// out2 = relu(agg @ W2 + b2), M=10000, K=N=256. 64x64 tile, 4x4/thread,
// float4 LDS fragment reads (As stride 68 keeps 16B alignment; 2-way bank
// aliasing only, which is free on CDNA4).
__global__ __launch_bounds__(256) void k_gemm(const float* A, const float* B,
                                              const float* bias, float* C) {
    __shared__ float As[16][68];
    __shared__ float Bs[16][64];
    int tid  = threadIdx.x;
    int row0 = blockIdx.x * 64;
    int col0 = blockIdx.y * 64;
    float acc[4][4] = {};
    int am = tid >> 2, ak = (tid & 3) * 4;    // A loader: row am, 4 consecutive k
    int bk = tid >> 4, bn = (tid & 15) * 4;   // B loader: row bk, 4 consecutive n
    int ty = tid >> 4, tx = tid & 15;
    for (int k0 = 0; k0 < 256; k0 += 16) {
        float4 av = {0.f, 0.f, 0.f, 0.f};
        if (row0 + am < N_NODES)
            av = *(const float4*)(A + (size_t)(row0 + am) * 256 + k0 + ak);
        As[ak + 0][am] = av.x; As[ak + 1][am] = av.y;
        As[ak + 2][am] = av.z; As[ak + 3][am] = av.w;
        float4 bv = *(const float4*)(B + (size_t)(k0 + bk) * 256 + col0 + bn);
        *(float4*)&Bs[bk][bn] = bv;
        __syncthreads();
        #pragma unroll
        for (int k = 0; k < 16; k++) {
            float4 a4 = *(const float4*)&As[k][ty * 4];
            float4 b4 = *(const float4*)&Bs[k][tx * 4];
            float a[4] = {a4.x, a4.y, a4.z, a4.w};
            float b[4] = {b4.x, b4.y, b4.z, b4.w};
            #pragma unroll
            for (int m = 0; m < 4; m++)
                #pragma unroll
                for (int n = 0; n < 4; n++) acc[m][n] += a[m] * b[n];
        }
        __syncthreads();
    }
    #pragma unroll
    for (int m = 0; m < 4; m++) {
        int r = row0 + ty * 4 + m;
        if (r >= N_NODES) continue;
        #pragma unroll
        for (int n = 0; n < 4; n++) {
            int c = col0 + tx * 4 + n;
            C[(size_t)r * 256 + c] = fmaxf(acc[m][n] + bias[c], 0.0f);
        }
    }
}

__global__ void k_pool(const float* out2, const int* gstart, float* gfeat) {
    int g = blockIdx.x, c = threadIdx.x;
    int lo = gstart[g], hi = gstart[g + 1];
    float sum = 0.0f;
    for (int i = lo; i < hi; i++) sum += out2[(size_t)i * F + c];
    int cnt = hi - lo; if (cnt < 1) cnt = 1;
    gfeat[g * F + c] = sum / (float)cnt;
}

__global__ void k_head(const float* gfeat,
                       const float* W3, const float* b3, const float* W4, const float* b4,
                       const float* W5, const float* b5, const float* W6, const float* b6,
                       const float* W7, const float* b7, float* y) {
    __shared__ float a[256], b[256];
    int g = blockIdx.x, t = threadIdx.x;
    a[t] = gfeat[g * 256 + t];
    __syncthreads();
    if (t < 128) { float acc = b3[t]; for (int k = 0; k < 256; k++) acc += a[k] * W3[k * 128 + t]; b[t] = fmaxf(acc, 0.f); }
    __syncthreads();
    if (t < 128) { float acc = b4[t]; for (int k = 0; k < 128; k++) acc += b[k] * W4[k * 128 + t]; a[t] = fmaxf(acc, 0.f); }
    __syncthreads();
    if (t < 64)  { float acc = b5[t]; for (int k = 0; k < 128; k++) acc += a[k] * W5[k * 64 + t];  b[t] = fmaxf(acc, 0.f); }
    __syncthreads();
    if (t < 32)  { float acc = b6[t]; for (int k = 0; k < 64;  k++) acc += b[k] * W6[k * 32 + t];  a[t] = fmaxf(acc, 0.f); }
    __syncthreads();
    if (t == 0)  { float acc = b7[0]; for (int k = 0; k < 32;  k++) acc += a[k] * W7[k]; y[g] = acc; }
}

extern "C" void kernel_launch(void* const* d_in, const int* in_sizes, int n_in,
                              void* d_out, int out_size, void* d_ws, size_t ws_size,
                              hipStream_t stream) {
    const float* x     = (const float*)d_in[0];
    const int*   edges = (const int*)d_in[1];
    const int*   batch = (const int*)d_in[2];
    const float* W1 = (const float*)d_in[3];  const float* b1 = (const float*)d_in[4];
    const float* W2 = (const float*)d_in[5];  const float* b2 = (const float*)d_in[6];
    const float* W3 = (const float*)d_in[7];  const float* b3 = (const float*)d_in[8];
    const float* W4 = (const float*)d_in[9];  const float* b4 = (const float*)d_in[10];
    const float* W5 = (const float*)d_in[11]; const float* b5 = (const float*)d_in[12];
    const float* W6 = (const float*)d_in[13]; const float* b6 = (const float*)d_in[14];
    const float* W7 = (const float*)d_in[15]; const float* b7 = (const float*)d_in[16];
    float* y = (float*)d_out;

    const int* esrc = edges;
    const int* edst = edges + N_EDGES;

    char* w = (char*)d_ws;
    size_t off = 0;
    auto alloc = [&](size_t bytes) { char* p = w + off; off += (bytes + 1023) & ~size_t(1023); return p; };
    float* deg_dinv = (float*)alloc(N_NODES * 4);
    float* svec     = (float*)alloc(N_NODES * 4);
    int*   cnti     = (int*)  alloc(N_NODES * 4);
    int*   offs     = (int*)  alloc(N_NODES * 4);
    int*   cursor   = (int*)  alloc(N_NODES * 4);
    int*   gstart   = (int*)  alloc((N_GRAPHS + 1) * 4);
    int*   csr      = (int*)  alloc(N_EDGES * 4);
    float* out1s    = (float*)alloc((size_t)N_NODES * F * 4);
    float* aggb     = (float*)alloc((size_t)N_NODES * F * 4);
    float* out2     = (float*)alloc((size_t)N_NODES * F * 4);
    float* gfeat    = (float*)alloc((size_t)N_GRAPHS * F * 4);
    (void)ws_size; (void)in_sizes; (void)n_in; (void)out_size;

    const int TB = 256;
    int gbN = (N_NODES + TB - 1) / TB;       // 40
    int gbE = (N_EDGES + TB - 1) / TB;       // 1250

    hipLaunchKernelGGL(k_prep,   dim3(gbN), dim3(TB), 0, stream, batch, deg_dinv, svec, gstart);
    hipLaunchKernelGGL(k_deg,    dim3(gbE), dim3(TB), 0, stream, edst, deg_dinv);
    hipLaunchKernelGGL(k_dinv,   dim3(gbN), dim3(TB), 0, stream, deg_dinv, cnti);
    hipLaunchKernelGGL(k_s,      dim3(gbE), dim3(TB), 0, stream, esrc, edst, x, deg_dinv, svec);
    hipLaunchKernelGGL(k_scan,   dim3(1),   dim3(TB), 0, stream, cnti, offs, cursor);
    hipLaunchKernelGGL(k_fill,   dim3(gbE), dim3(TB), 0, stream, esrc, edst, cursor, csr);
    hipLaunchKernelGGL(k_out1,   dim3((N_NODES * F + TB - 1) / TB), dim3(TB), 0, stream,
                       svec, deg_dinv, x, W1, b1, out1s);
    hipLaunchKernelGGL(k_agg,    dim3((N_NODES * 64 + TB - 1) / TB), dim3(TB), 0, stream,
                       out1s, deg_dinv, offs, cnti, csr, aggb);
    hipLaunchKernelGGL(k_gemm,   dim3((N_NODES + 63) / 64, 4), dim3(TB), 0, stream,
                       aggb, W2, b2, out2);
    hipLaunchKernelGGL(k_pool,   dim3(N_GRAPHS), dim3(F), 0, stream, out2, gstart, gfeat);
    hipLaunchKernelGGL(k_head,   dim3(N_GRAPHS), dim3(TB), 0, stream,
                       gfeat, W3, b3, W4, b4, W5, b5, W6, b6, W7, b7, y);
}

// Round 3
// 254.920 us; speedup vs baseline: 1.2625x; 1.2625x over previous
//
#include <hip/hip_runtime.h>

#define N_NODES  10000
#define N_EDGES  320000
#define N_GRAPHS 64
#define F 256
#define POOL_SPLIT 8

// ---------------- pipeline ----------------
// layer1 factors to scalars: h1[i,:] = relu(sfin[i]*W1 + b1),
//   sfin[i] = dinv[i]*(sum_{e:dst=i} dinv[src]*x[src] + dinv[i]*x[i])
// layer2 agg NEVER materializes h1: per gathered edge, recompute
//   relu(sfin[sv]*W1+b1)*dinv[sv] from an 8B (sfin,dinv) load with W1,b1
//   held in registers. Then one [10000,256]x[256,256] GEMM (+bias, relu).
// pool: 8-way split partial sums (no atomics). head: per-graph MLP.

__global__ void k_prep(const int* batch, int* cnti, float* s, int* gstart) {
    int i = blockIdx.x * blockDim.x + threadIdx.x;
    if (i >= N_NODES) return;
    cnti[i] = 0;
    s[i] = 0.0f;
    int b = batch[i];
    if (i == 0) {
        for (int g = 0; g <= b; g++) gstart[g] = 0;
    } else {
        int bp = batch[i - 1];
        for (int g = bp + 1; g <= b; g++) gstart[g] = i;
    }
    if (i == N_NODES - 1) {
        for (int g = b + 1; g <= N_GRAPHS; g++) gstart[g] = N_NODES;
    }
}

__global__ void k_deg(const int* dst, int* cnti) {
    int e = blockIdx.x * blockDim.x + threadIdx.x;
    if (e < N_EDGES) atomicAdd(&cnti[dst[e]], 1);
}

// single-block: exclusive scan cnti -> offs (seeds cursor), dinv = 1/sqrt(deg+1)
__global__ void k_scan(const int* cnti, int* offs, int* cursor, float* dinv) {
    __shared__ int part[256];
    int t = threadIdx.x;
    const int CH = 40;                 // 256*40 >= 10000
    int lo = t * CH, hi = lo + CH;
    if (hi > N_NODES) hi = N_NODES;
    if (lo > N_NODES) lo = N_NODES;
    int sum = 0;
    for (int i = lo; i < hi; i++) sum += cnti[i];
    part[t] = sum;
    __syncthreads();
    for (int off = 1; off < 256; off <<= 1) {
        int v = (t >= off) ? part[t - off] : 0;
        __syncthreads();
        if (t >= off) part[t] += v;
        __syncthreads();
    }
    int base = (t == 0) ? 0 : part[t - 1];
    for (int i = lo; i < hi; i++) {
        offs[i] = base; cursor[i] = base; base += cnti[i];
        dinv[i] = 1.0f / sqrtf((float)(cnti[i] + 1));
    }
}

// one edge pass: CSR bucket fill + scalar layer-1 scatter
__global__ void k_edge(const int* src, const int* dst, const float* x,
                       const float* dinv, int* cursor, int* csr, float* s) {
    int e = blockIdx.x * blockDim.x + threadIdx.x;
    if (e >= N_EDGES) return;
    int sv = src[e], dv = dst[e];
    int pos = atomicAdd(&cursor[dv], 1);
    csr[pos] = sv;
    atomicAdd(&s[dv], dinv[sv] * x[sv]);
}

__global__ void k_sfin(const float* s, const float* dinv, const float* x, float2* sd) {
    int i = blockIdx.x * blockDim.x + threadIdx.x;
    if (i >= N_NODES) return;
    float di = dinv[i];
    sd[i] = make_float2(di * (s[i] + di * x[i]), di);
}

// one wave per node; lane owns channels [4*lane, 4*lane+4).
// agg[i,:] = dinv[i]*( relu(sfin[i]*W1+b1)*dinv[i] + sum_sv relu(sfin[sv]*W1+b1)*dinv[sv] )
#define EDGE_TERM(t)                                  \
    acc.x += fmaxf(fmaf((t).x, w.x, bv.x), 0.f) * (t).y; \
    acc.y += fmaxf(fmaf((t).x, w.y, bv.y), 0.f) * (t).y; \
    acc.z += fmaxf(fmaf((t).x, w.z, bv.z), 0.f) * (t).y; \
    acc.w += fmaxf(fmaf((t).x, w.w, bv.w), 0.f) * (t).y;

__global__ __launch_bounds__(256) void k_agg(const float2* sd, const float* W1, const float* b1,
                                             const int* offs, const int* cnti, const int* csr,
                                             float* agg) {
    int wid  = (blockIdx.x * blockDim.x + threadIdx.x) >> 6;
    int lane = threadIdx.x & 63;
    if (wid >= N_NODES) return;
    float4 w  = ((const float4*)W1)[lane];
    float4 bv = ((const float4*)b1)[lane];
    float2 self = sd[wid];
    float4 acc = {0.f, 0.f, 0.f, 0.f};
    EDGE_TERM(self)                       // self-loop term (weight dinv_i applied at end too)
    int lo = offs[wid], n = cnti[wid];
    int j = 0;
    for (; j + 3 < n; j += 4) {
        int s0 = csr[lo + j],     s1 = csr[lo + j + 1];
        int s2 = csr[lo + j + 2], s3 = csr[lo + j + 3];
        float2 t0 = sd[s0], t1 = sd[s1], t2 = sd[s2], t3 = sd[s3];
        EDGE_TERM(t0) EDGE_TERM(t1) EDGE_TERM(t2) EDGE_TERM(t3)
    }
    for (; j < n; j++) {
        float2 t = sd[csr[lo + j]];
        EDGE_TERM(t)
    }
    float di = self.y;
    float4 o; o.x = acc.x * di; o.y = acc.y * di; o.z = acc.z * di; o.w = acc.w * di;
    ((float4*)(agg + (size_t)wid * F))[lane] = o;
}

// out2 = relu(agg @ W2 + b2), M=10000, K=N=256. 64x64 tile, 4x4/thread,
// float4 LDS fragment reads (As stride 68 keeps 16B alignment).
__global__ __launch_bounds__(256) void k_gemm(const float* A, const float* B,
                                              const float* bias, float* C) {
    __shared__ float As[16][68];
    __shared__ float Bs[16][64];
    int tid  = threadIdx.x;
    int row0 = blockIdx.x * 64;
    int col0 = blockIdx.y * 64;
    float acc[4][4] = {};
    int am = tid >> 2, ak = (tid & 3) * 4;
    int bk = tid >> 4, bn = (tid & 15) * 4;
    int ty = tid >> 4, tx = tid & 15;
    for (int k0 = 0; k0 < 256; k0 += 16) {
        float4 av = {0.f, 0.f, 0.f, 0.f};
        if (row0 + am < N_NODES)
            av = *(const float4*)(A + (size_t)(row0 + am) * 256 + k0 + ak);
        As[ak + 0][am] = av.x; As[ak + 1][am] = av.y;
        As[ak + 2][am] = av.z; As[ak + 3][am] = av.w;
        float4 bvv = *(const float4*)(B + (size_t)(k0 + bk) * 256 + col0 + bn);
        *(float4*)&Bs[bk][bn] = bvv;
        __syncthreads();
        #pragma unroll
        for (int k = 0; k < 16; k++) {
            float4 a4 = *(const float4*)&As[k][ty * 4];
            float4 b4 = *(const float4*)&Bs[k][tx * 4];
            float a[4] = {a4.x, a4.y, a4.z, a4.w};
            float b[4] = {b4.x, b4.y, b4.z, b4.w};
            #pragma unroll
            for (int m = 0; m < 4; m++)
                #pragma unroll
                for (int n = 0; n < 4; n++) acc[m][n] += a[m] * b[n];
        }
        __syncthreads();
    }
    #pragma unroll
    for (int m = 0; m < 4; m++) {
        int r = row0 + ty * 4 + m;
        if (r >= N_NODES) continue;
        #pragma unroll
        for (int n = 0; n < 4; n++) {
            int c = col0 + tx * 4 + n;
            C[(size_t)r * 256 + c] = fmaxf(acc[m][n] + bias[c], 0.0f);
        }
    }
}

// 8-way split partial sums per graph; every slot written (no init needed)
__global__ void k_pool(const float* out2, const int* gstart, float* partial) {
    int g = blockIdx.x, sp = blockIdx.y, c = threadIdx.x;
    int lo = gstart[g], hi = gstart[g + 1];
    int len = hi - lo;
    int chunk = (len + POOL_SPLIT - 1) / POOL_SPLIT;
    int a = lo + sp * chunk;
    int b = a + chunk; if (b > hi) b = hi;
    float sum = 0.0f;
    for (int i = a; i < b; i++) sum += out2[(size_t)i * F + c];
    partial[((size_t)g * POOL_SPLIT + sp) * F + c] = sum;
}

__global__ void k_head(const float* partial, const int* gstart,
                       const float* W3, const float* b3, const float* W4, const float* b4,
                       const float* W5, const float* b5, const float* W6, const float* b6,
                       const float* W7, const float* b7, float* y) {
    __shared__ float a[256], b[256];
    int g = blockIdx.x, t = threadIdx.x;
    float sum = 0.0f;
    #pragma unroll
    for (int sp = 0; sp < POOL_SPLIT; sp++)
        sum += partial[((size_t)g * POOL_SPLIT + sp) * F + t];
    int cnt = gstart[g + 1] - gstart[g]; if (cnt < 1) cnt = 1;
    a[t] = sum / (float)cnt;
    __syncthreads();
    if (t < 128) { float acc = b3[t]; for (int k = 0; k < 256; k++) acc += a[k] * W3[k * 128 + t]; b[t] = fmaxf(acc, 0.f); }
    __syncthreads();
    if (t < 128) { float acc = b4[t]; for (int k = 0; k < 128; k++) acc += b[k] * W4[k * 128 + t]; a[t] = fmaxf(acc, 0.f); }
    __syncthreads();
    if (t < 64)  { float acc = b5[t]; for (int k = 0; k < 128; k++) acc += a[k] * W5[k * 64 + t];  b[t] = fmaxf(acc, 0.f); }
    __syncthreads();
    if (t < 32)  { float acc = b6[t]; for (int k = 0; k < 64;  k++) acc += b[k] * W6[k * 32 + t];  a[t] = fmaxf(acc, 0.f); }
    __syncthreads();
    if (t == 0)  { float acc = b7[0]; for (int k = 0; k < 32;  k++) acc += a[k] * W7[k]; y[g] = acc; }
}

extern "C" void kernel_launch(void* const* d_in, const int* in_sizes, int n_in,
                              void* d_out, int out_size, void* d_ws, size_t ws_size,
                              hipStream_t stream) {
    const float* x     = (const float*)d_in[0];
    const int*   edges = (const int*)d_in[1];
    const int*   batch = (const int*)d_in[2];
    const float* W1 = (const float*)d_in[3];  const float* b1 = (const float*)d_in[4];
    const float* W2 = (const float*)d_in[5];  const float* b2 = (const float*)d_in[6];
    const float* W3 = (const float*)d_in[7];  const float* b3 = (const float*)d_in[8];
    const float* W4 = (const float*)d_in[9];  const float* b4 = (const float*)d_in[10];
    const float* W5 = (const float*)d_in[11]; const float* b5 = (const float*)d_in[12];
    const float* W6 = (const float*)d_in[13]; const float* b6 = (const float*)d_in[14];
    const float* W7 = (const float*)d_in[15]; const float* b7 = (const float*)d_in[16];
    float* y = (float*)d_out;

    const int* esrc = edges;
    const int* edst = edges + N_EDGES;

    char* w = (char*)d_ws;
    size_t off = 0;
    auto alloc = [&](size_t bytes) { char* p = w + off; off += (bytes + 1023) & ~size_t(1023); return p; };
    int*    cnti    = (int*)   alloc(N_NODES * 4);
    float*  svec    = (float*) alloc(N_NODES * 4);
    int*    offs    = (int*)   alloc(N_NODES * 4);
    int*    cursor  = (int*)   alloc(N_NODES * 4);
    float*  dinv    = (float*) alloc(N_NODES * 4);
    int*    gstart  = (int*)   alloc((N_GRAPHS + 1) * 4);
    int*    csr     = (int*)   alloc(N_EDGES * 4);
    float2* sd      = (float2*)alloc((size_t)N_NODES * 8);
    float*  aggb    = (float*) alloc((size_t)N_NODES * F * 4);
    float*  out2    = (float*) alloc((size_t)N_NODES * F * 4);
    float*  partial = (float*) alloc((size_t)N_GRAPHS * POOL_SPLIT * F * 4);
    (void)ws_size; (void)in_sizes; (void)n_in; (void)out_size;

    const int TB = 256;
    int gbN = (N_NODES + TB - 1) / TB;       // 40
    int gbE = (N_EDGES + TB - 1) / TB;       // 1250

    hipLaunchKernelGGL(k_prep, dim3(gbN), dim3(TB), 0, stream, batch, cnti, svec, gstart);
    hipLaunchKernelGGL(k_deg,  dim3(gbE), dim3(TB), 0, stream, edst, cnti);
    hipLaunchKernelGGL(k_scan, dim3(1),   dim3(TB), 0, stream, cnti, offs, cursor, dinv);
    hipLaunchKernelGGL(k_edge, dim3(gbE), dim3(TB), 0, stream, esrc, edst, x, dinv, cursor, csr, svec);
    hipLaunchKernelGGL(k_sfin, dim3(gbN), dim3(TB), 0, stream, svec, dinv, x, sd);
    hipLaunchKernelGGL(k_agg,  dim3((N_NODES * 64 + TB - 1) / TB), dim3(TB), 0, stream,
                       sd, W1, b1, offs, cnti, csr, aggb);
    hipLaunchKernelGGL(k_gemm, dim3((N_NODES + 63) / 64, 4), dim3(TB), 0, stream,
                       aggb, W2, b2, out2);
    hipLaunchKernelGGL(k_pool, dim3(N_GRAPHS, POOL_SPLIT), dim3(F), 0, stream, out2, gstart, partial);
    hipLaunchKernelGGL(k_head, dim3(N_GRAPHS), dim3(TB), 0, stream,
                       partial, gstart, W3, b3, W4, b4, W5, b5, W6, b6, W7, b7, y);
}